// Round 2
// baseline (413.541 us; speedup 1.0000x reference)
//
#include <hip/hip_runtime.h>
#include <hip/hip_bf16.h>

#define NN 50000
#define NE 640000

// ---------------- CSR (dest-keyed) build ----------------

__global__ void count_kernel(const int* __restrict__ col, int* __restrict__ cnt, int n) {
  int i = blockIdx.x * blockDim.x + threadIdx.x;
  if (i < n) atomicAdd(&cnt[col[i]], 1);
}

__global__ void scan_kernel(const int* __restrict__ cnt, int* __restrict__ row_ptr,
                            float* __restrict__ dis, int n) {
  const int T = 1024;
  __shared__ int s[T];
  const int tid = threadIdx.x;
  const int chunk = (n + T - 1) / T;
  const int base = tid * chunk;
  int sum = 0;
  for (int i = 0; i < chunk; ++i) {
    int idx = base + i;
    if (idx < n) sum += cnt[idx];
  }
  s[tid] = sum;
  __syncthreads();
  for (int off = 1; off < T; off <<= 1) {
    int v = (tid >= off) ? s[tid - off] : 0;
    __syncthreads();
    s[tid] += v;
    __syncthreads();
  }
  int run = (tid == 0) ? 0 : s[tid - 1];
  for (int i = 0; i < chunk; ++i) {
    int idx = base + i;
    if (idx < n) {
      row_ptr[idx] = run;
      int c = cnt[idx];
      run += c;
      dis[idx] = rsqrtf((float)(c + 1));  // self-loop => deg = cnt+1 >= 1
    }
  }
  if (tid == T - 1) row_ptr[n] = s[T - 1];
}

__global__ void fill_kernel(const int* __restrict__ row, const int* __restrict__ col,
                            const int* __restrict__ row_ptr, int* __restrict__ fillc,
                            int* __restrict__ csr, int n) {
  int i = blockIdx.x * blockDim.x + threadIdx.x;
  if (i < n) {
    int c = col[i];
    int p = row_ptr[c] + atomicAdd(&fillc[c], 1);
    csr[p] = row[i];
  }
}

// ---------------- GEMM ----------------
// out[r][c] = dis[r] * sum_{k<128} X[r][k] * W[k*ldw + wc0 + c],  c < 64.
// BM=64, BN=64, K=128 (2 x 64). 256 threads, 4x4 per thread.

__device__ __forceinline__ float bfu(unsigned short u) {
  union { unsigned int i; float f; } v;
  v.i = ((unsigned int)u) << 16;
  return v.f;
}

template <bool BF16IN>
__global__ __launch_bounds__(256) void gemm_scale_kernel(
    const void* __restrict__ Xv, const float* __restrict__ W, int ldw, int wc0,
    const float* __restrict__ dis, float* __restrict__ out, int M) {
  __shared__ float Ws[128][64];  // 32 KB
  __shared__ float Xs[64][68];   // 17.4 KB (pad 4 -> conflict-free)

  const int t = threadIdx.x;
  const int rb = blockIdx.x * 64;

  // stage W tile [128][64]
  for (int f = t; f < 128 * 16; f += 256) {
    int k = f >> 4, cq = f & 15;
    *reinterpret_cast<float4*>(&Ws[k][cq * 4]) =
        *reinterpret_cast<const float4*>(&W[(size_t)k * ldw + wc0 + cq * 4]);
  }

  const int tcol = t & 15;
  const int trow = t >> 4;
  float acc[4][4] = {};

  for (int kt = 0; kt < 2; ++kt) {
    __syncthreads();  // prev compute done (covers Ws staging on kt=0)
    for (int f = t; f < 64 * 16; f += 256) {
      int r = f >> 4, kq = f & 15;
      float4 v = {0.f, 0.f, 0.f, 0.f};
      int gr = rb + r;
      if (gr < M) {
        if constexpr (BF16IN) {
          const unsigned short* X = (const unsigned short*)Xv;
          ushort4 u = *reinterpret_cast<const ushort4*>(&X[(size_t)gr * 128 + kt * 64 + kq * 4]);
          v = make_float4(bfu(u.x), bfu(u.y), bfu(u.z), bfu(u.w));
        } else {
          const float* X = (const float*)Xv;
          v = *reinterpret_cast<const float4*>(&X[(size_t)gr * 128 + kt * 64 + kq * 4]);
        }
      }
      *reinterpret_cast<float4*>(&Xs[r][kq * 4]) = v;
    }
    __syncthreads();
#pragma unroll 4
    for (int kc = 0; kc < 16; ++kc) {
      float4 xv[4], wv[4];
#pragma unroll
      for (int i = 0; i < 4; ++i)
        xv[i] = *reinterpret_cast<const float4*>(&Xs[trow * 4 + i][kc * 4]);
#pragma unroll
      for (int j = 0; j < 4; ++j)
        wv[j] = *reinterpret_cast<const float4*>(&Ws[kt * 64 + kc * 4 + j][tcol * 4]);
#pragma unroll
      for (int i = 0; i < 4; ++i) {
        const float x0 = xv[i].x, x1 = xv[i].y, x2 = xv[i].z, x3 = xv[i].w;
        acc[i][0] += x0 * wv[0].x + x1 * wv[1].x + x2 * wv[2].x + x3 * wv[3].x;
        acc[i][1] += x0 * wv[0].y + x1 * wv[1].y + x2 * wv[2].y + x3 * wv[3].y;
        acc[i][2] += x0 * wv[0].z + x1 * wv[1].z + x2 * wv[2].z + x3 * wv[3].z;
        acc[i][3] += x0 * wv[0].w + x1 * wv[1].w + x2 * wv[2].w + x3 * wv[3].w;
      }
    }
  }

#pragma unroll
  for (int i = 0; i < 4; ++i) {
    int r = rb + trow * 4 + i;
    if (r < M) {
      float d = dis[r];
      float4 o = {acc[i][0] * d, acc[i][1] * d, acc[i][2] * d, acc[i][3] * d};
      *reinterpret_cast<float4*>(&out[(size_t)r * 64 + tcol * 4]) = o;
    }
  }
}

// ---------------- Aggregation ----------------
// out[node*ldo + oc0 + lane] = act( dis[node]*(sum_src Hs[src][lane] + Hs[node][lane]) + bias[lane] )
// Hs is [n][64] f32. One wave per node, lane = channel.

template <bool BF16OUT>
__global__ __launch_bounds__(256) void agg_kernel(
    const float* __restrict__ Hs, const int* __restrict__ row_ptr,
    const int* __restrict__ csr, const float* __restrict__ dis,
    const float* __restrict__ bias, void* __restrict__ outv,
    int ldo, int oc0, int relu, int n) {
  const int lane = threadIdx.x & 63;
  const int node = blockIdx.x * 4 + (threadIdx.x >> 6);
  if (node >= n) return;

  float acc = Hs[(size_t)node * 64 + lane];  // self-loop term
  const int s0 = row_ptr[node], s1 = row_ptr[node + 1];
  for (int e = s0; e < s1; e += 64) {
    int m = s1 - e;
    if (m > 64) m = 64;
    int idx = 0;
    if (lane < m) idx = csr[e + lane];
    for (int j = 0; j < m; ++j) {
      int src = __shfl(idx, j);
      acc += Hs[(size_t)src * 64 + lane];
    }
  }
  float o = acc * dis[node] + bias[lane];
  if (relu) o = fmaxf(o, 0.0f);
  if constexpr (BF16OUT) {
    __hip_bfloat16* out = (__hip_bfloat16*)outv;
    out[(size_t)node * ldo + oc0 + lane] = __float2bfloat16(o);
  } else {
    float* out = (float*)outv;
    out[(size_t)node * ldo + oc0 + lane] = o;
  }
}

// ---------------- launch ----------------

extern "C" void kernel_launch(void* const* d_in, const int* in_sizes, int n_in,
                              void* d_out, int out_size, void* d_ws, size_t ws_size,
                              hipStream_t stream) {
  const float* x  = (const float*)d_in[0];
  const int*   ei = (const int*)d_in[1];
  const float* W1 = (const float*)d_in[2];
  const float* b1 = (const float*)d_in[3];
  const float* W2 = (const float*)d_in[4];
  const float* b2 = (const float*)d_in[5];
  float* out = (float*)d_out;

  const int* row = ei;        // source nodes
  const int* col = ei + NE;   // destination nodes

  char* ws = (char*)d_ws;
  size_t off = 0;
  auto alloc = [&](size_t bytes) -> void* {
    off = (off + 255) & ~(size_t)255;
    void* p = ws + off;
    off += bytes;
    return p;
  };

  int* cnt     = (int*)alloc((size_t)2 * NN * sizeof(int));  // cnt | fillc contiguous
  int* fillc   = cnt + NN;
  int* row_ptr = (int*)alloc((size_t)(NN + 1) * sizeof(int));
  int* csr     = (int*)alloc((size_t)NE * sizeof(int));
  float* dis   = (float*)alloc((size_t)NN * sizeof(float));
  float* Htmp  = (float*)alloc((size_t)NN * 64 * sizeof(float));  // GEMM output slice, reused 3x

  // Z1 dtype chosen by available workspace (ws_size is constant -> deterministic).
  size_t z1_f32_need;
  {
    size_t o2 = (off + 255) & ~(size_t)255;
    z1_f32_need = o2 + (size_t)NN * 128 * sizeof(float);
  }
  const bool z1f32 = (ws_size >= z1_f32_need);
  void* Z1 = alloc((size_t)NN * 128 * (z1f32 ? sizeof(float) : sizeof(__hip_bfloat16)));

  hipMemsetAsync(cnt, 0, (size_t)2 * NN * sizeof(int), stream);
  count_kernel<<<NE / 256, 256, 0, stream>>>(col, cnt, NE);
  scan_kernel<<<1, 1024, 0, stream>>>(cnt, row_ptr, dis, NN);
  fill_kernel<<<NE / 256, 256, 0, stream>>>(row, col, row_ptr, fillc, csr, NE);

  const int gx = (NN + 63) / 64;
  const int ga = (NN + 3) / 4;

  // ---- Layer 1: two 64-col passes ----
  for (int h = 0; h < 2; ++h) {
    gemm_scale_kernel<false><<<gx, 256, 0, stream>>>(x, W1, 128, h * 64, dis, Htmp, NN);
    if (z1f32)
      agg_kernel<false><<<ga, 256, 0, stream>>>(Htmp, row_ptr, csr, dis, b1 + h * 64,
                                                Z1, 128, h * 64, 1, NN);
    else
      agg_kernel<true><<<ga, 256, 0, stream>>>(Htmp, row_ptr, csr, dis, b1 + h * 64,
                                               Z1, 128, h * 64, 1, NN);
  }

  // ---- Layer 2 ----
  if (z1f32)
    gemm_scale_kernel<false><<<gx, 256, 0, stream>>>(Z1, W2, 64, 0, dis, Htmp, NN);
  else
    gemm_scale_kernel<true><<<gx, 256, 0, stream>>>(Z1, W2, 64, 0, dis, Htmp, NN);
  agg_kernel<false><<<ga, 256, 0, stream>>>(Htmp, row_ptr, csr, dis, b2, out, 64, 0, 0, NN);
}

// Round 3
// 300.334 us; speedup vs baseline: 1.3769x; 1.3769x over previous
//
#include <hip/hip_runtime.h>
#include <hip/hip_bf16.h>

#define NN 50000
#define NE 640000
#define NB 196  // ceil((NN+1)/256)

// ---------------- CSR (dest-keyed) build ----------------

__global__ void count_kernel(const int* __restrict__ col, int* __restrict__ cnt, int n) {
  int i = blockIdx.x * blockDim.x + threadIdx.x;
  if (i < n) atomicAdd(&cnt[col[i]], 1);
}

// Hierarchical scan: per-block sums -> scan of block sums -> per-block write.

__global__ __launch_bounds__(256) void block_sum_kernel(const int* __restrict__ cnt,
                                                        int* __restrict__ bsum, int n) {
  __shared__ int ws[4];
  const int tid = threadIdx.x;
  const int t = blockIdx.x * 256 + tid;
  int c = (t < n) ? cnt[t] : 0;
  int s = c;
#pragma unroll
  for (int off = 1; off < 64; off <<= 1) s += __shfl_xor(s, off);
  if ((tid & 63) == 0) ws[tid >> 6] = s;
  __syncthreads();
  if (tid == 0) bsum[blockIdx.x] = ws[0] + ws[1] + ws[2] + ws[3];
}

__global__ __launch_bounds__(256) void scan_bsum_kernel(const int* __restrict__ bsum,
                                                        int* __restrict__ boff, int nb) {
  __shared__ int s[256];
  const int tid = threadIdx.x;
  int v = (tid < nb) ? bsum[tid] : 0;
  s[tid] = v;
  __syncthreads();
  for (int off = 1; off < 256; off <<= 1) {
    int u = (tid >= off) ? s[tid - off] : 0;
    __syncthreads();
    s[tid] += u;
    __syncthreads();
  }
  if (tid < nb) boff[tid] = s[tid] - v;  // exclusive
}

__global__ __launch_bounds__(256) void write_rowptr_kernel(
    const int* __restrict__ cnt, const int* __restrict__ boff,
    int* __restrict__ row_ptr, float* __restrict__ dis, int n) {
  __shared__ int wsum[4];
  const int tid = threadIdx.x;
  const int t = blockIdx.x * 256 + tid;
  const int lane = tid & 63, w = tid >> 6;
  int c = (t < n) ? cnt[t] : 0;
  int inc = c;
#pragma unroll
  for (int off = 1; off < 64; off <<= 1) {
    int u = __shfl_up(inc, off);
    if (lane >= off) inc += u;
  }
  if (lane == 63) wsum[w] = inc;
  __syncthreads();
  int wo = 0;
  for (int i = 0; i < w; ++i) wo += wsum[i];
  int excl = boff[blockIdx.x] + wo + inc - c;
  if (t <= n) row_ptr[t] = excl;  // t==n lands here with c==0 -> total edge count
  if (t < n) dis[t] = rsqrtf((float)(c + 1));
}

__global__ void fill_kernel(const int* __restrict__ row, const int* __restrict__ col,
                            const int* __restrict__ row_ptr, int* __restrict__ fillc,
                            int* __restrict__ csr, int n) {
  int i = blockIdx.x * blockDim.x + threadIdx.x;
  if (i < n) {
    int c = col[i];
    int p = row_ptr[c] + atomicAdd(&fillc[c], 1);
    csr[p] = row[i];
  }
}

// ---------------- GEMM ----------------
// out[r][c] = dis[r] * sum_{k<128} X[r][k] * W[k*ldw + wc0 + c],  c < 64.
// BM=64, BN=64, K=128 (2 x 64). 256 threads, 4x4 per thread.

__device__ __forceinline__ float bfu(unsigned short u) {
  union { unsigned int i; float f; } v;
  v.i = ((unsigned int)u) << 16;
  return v.f;
}

template <bool BF16IN>
__global__ __launch_bounds__(256) void gemm_scale_kernel(
    const void* __restrict__ Xv, const float* __restrict__ W, int ldw, int wc0,
    const float* __restrict__ dis, float* __restrict__ out, int M) {
  __shared__ float Ws[128][64];  // 32 KB
  __shared__ float Xs[64][68];   // 17.4 KB (pad 4 -> conflict-free)

  const int t = threadIdx.x;
  const int rb = blockIdx.x * 64;

  for (int f = t; f < 128 * 16; f += 256) {
    int k = f >> 4, cq = f & 15;
    *reinterpret_cast<float4*>(&Ws[k][cq * 4]) =
        *reinterpret_cast<const float4*>(&W[(size_t)k * ldw + wc0 + cq * 4]);
  }

  const int tcol = t & 15;
  const int trow = t >> 4;
  float acc[4][4] = {};

  for (int kt = 0; kt < 2; ++kt) {
    __syncthreads();  // prev compute done (covers Ws staging on kt=0)
    for (int f = t; f < 64 * 16; f += 256) {
      int r = f >> 4, kq = f & 15;
      float4 v = {0.f, 0.f, 0.f, 0.f};
      int gr = rb + r;
      if (gr < M) {
        if constexpr (BF16IN) {
          const unsigned short* X = (const unsigned short*)Xv;
          ushort4 u = *reinterpret_cast<const ushort4*>(&X[(size_t)gr * 128 + kt * 64 + kq * 4]);
          v = make_float4(bfu(u.x), bfu(u.y), bfu(u.z), bfu(u.w));
        } else {
          const float* X = (const float*)Xv;
          v = *reinterpret_cast<const float4*>(&X[(size_t)gr * 128 + kt * 64 + kq * 4]);
        }
      }
      *reinterpret_cast<float4*>(&Xs[r][kq * 4]) = v;
    }
    __syncthreads();
#pragma unroll 4
    for (int kc = 0; kc < 16; ++kc) {
      float4 xv[4], wv[4];
#pragma unroll
      for (int i = 0; i < 4; ++i)
        xv[i] = *reinterpret_cast<const float4*>(&Xs[trow * 4 + i][kc * 4]);
#pragma unroll
      for (int j = 0; j < 4; ++j)
        wv[j] = *reinterpret_cast<const float4*>(&Ws[kt * 64 + kc * 4 + j][tcol * 4]);
#pragma unroll
      for (int i = 0; i < 4; ++i) {
        const float x0 = xv[i].x, x1 = xv[i].y, x2 = xv[i].z, x3 = xv[i].w;
        acc[i][0] += x0 * wv[0].x + x1 * wv[1].x + x2 * wv[2].x + x3 * wv[3].x;
        acc[i][1] += x0 * wv[0].y + x1 * wv[1].y + x2 * wv[2].y + x3 * wv[3].y;
        acc[i][2] += x0 * wv[0].z + x1 * wv[1].z + x2 * wv[2].z + x3 * wv[3].z;
        acc[i][3] += x0 * wv[0].w + x1 * wv[1].w + x2 * wv[2].w + x3 * wv[3].w;
      }
    }
  }

#pragma unroll
  for (int i = 0; i < 4; ++i) {
    int r = rb + trow * 4 + i;
    if (r < M) {
      float d = dis[r];
      float4 o = {acc[i][0] * d, acc[i][1] * d, acc[i][2] * d, acc[i][3] * d};
      *reinterpret_cast<float4*>(&out[(size_t)r * 64 + tcol * 4]) = o;
    }
  }
}

// ---------------- Aggregation ----------------
// out[node*ldo + oc0 + lane] = act( dis[node]*(sum_src Hs[src][lane] + Hs[node][lane]) + bias[lane] )
// Hs is [n][64] f32. One wave per node, lane = channel.

template <bool BF16OUT>
__global__ __launch_bounds__(256) void agg_kernel(
    const float* __restrict__ Hs, const int* __restrict__ row_ptr,
    const int* __restrict__ csr, const float* __restrict__ dis,
    const float* __restrict__ bias, void* __restrict__ outv,
    int ldo, int oc0, int relu, int n) {
  const int lane = threadIdx.x & 63;
  const int node = blockIdx.x * 4 + (threadIdx.x >> 6);
  if (node >= n) return;

  float acc = Hs[(size_t)node * 64 + lane];  // self-loop term
  const int s0 = row_ptr[node], s1 = row_ptr[node + 1];
  for (int e = s0; e < s1; e += 64) {
    int m = s1 - e;
    if (m > 64) m = 64;
    int idx = 0;
    if (lane < m) idx = csr[e + lane];
    for (int j = 0; j < m; ++j) {
      int src = __shfl(idx, j);
      acc += Hs[(size_t)src * 64 + lane];
    }
  }
  float o = acc * dis[node] + bias[lane];
  if (relu) o = fmaxf(o, 0.0f);
  if constexpr (BF16OUT) {
    __hip_bfloat16* out = (__hip_bfloat16*)outv;
    out[(size_t)node * ldo + oc0 + lane] = __float2bfloat16(o);
  } else {
    float* out = (float*)outv;
    out[(size_t)node * ldo + oc0 + lane] = o;
  }
}

// ---------------- launch ----------------

extern "C" void kernel_launch(void* const* d_in, const int* in_sizes, int n_in,
                              void* d_out, int out_size, void* d_ws, size_t ws_size,
                              hipStream_t stream) {
  const float* x  = (const float*)d_in[0];
  const int*   ei = (const int*)d_in[1];
  const float* W1 = (const float*)d_in[2];
  const float* b1 = (const float*)d_in[3];
  const float* W2 = (const float*)d_in[4];
  const float* b2 = (const float*)d_in[5];
  float* out = (float*)d_out;

  const int* row = ei;        // source nodes
  const int* col = ei + NE;   // destination nodes

  char* ws = (char*)d_ws;
  size_t off = 0;
  auto alloc = [&](size_t bytes) -> void* {
    off = (off + 255) & ~(size_t)255;
    void* p = ws + off;
    off += bytes;
    return p;
  };

  int* cnt     = (int*)alloc((size_t)2 * NN * sizeof(int));  // cnt | fillc contiguous
  int* fillc   = cnt + NN;
  int* row_ptr = (int*)alloc((size_t)(NN + 1) * sizeof(int));
  int* csr     = (int*)alloc((size_t)NE * sizeof(int));
  float* dis   = (float*)alloc((size_t)NN * sizeof(float));
  int* bsum    = (int*)alloc((size_t)NB * sizeof(int));
  int* boff    = (int*)alloc((size_t)NB * sizeof(int));
  float* Htmp  = (float*)alloc((size_t)NN * 64 * sizeof(float));  // GEMM output slice, reused 3x

  // Z1 dtype chosen by available workspace (ws_size is constant -> deterministic).
  size_t z1_f32_need;
  {
    size_t o2 = (off + 255) & ~(size_t)255;
    z1_f32_need = o2 + (size_t)NN * 128 * sizeof(float);
  }
  const bool z1f32 = (ws_size >= z1_f32_need);
  void* Z1 = alloc((size_t)NN * 128 * (z1f32 ? sizeof(float) : sizeof(__hip_bfloat16)));

  hipMemsetAsync(cnt, 0, (size_t)2 * NN * sizeof(int), stream);
  count_kernel<<<NE / 256, 256, 0, stream>>>(col, cnt, NE);
  block_sum_kernel<<<NB, 256, 0, stream>>>(cnt, bsum, NN);
  scan_bsum_kernel<<<1, 256, 0, stream>>>(bsum, boff, NB);
  write_rowptr_kernel<<<NB, 256, 0, stream>>>(cnt, boff, row_ptr, dis, NN);
  fill_kernel<<<NE / 256, 256, 0, stream>>>(row, col, row_ptr, fillc, csr, NE);

  const int gx = (NN + 63) / 64;
  const int ga = (NN + 3) / 4;

  // ---- Layer 1: two 64-col passes ----
  for (int h = 0; h < 2; ++h) {
    gemm_scale_kernel<false><<<gx, 256, 0, stream>>>(x, W1, 128, h * 64, dis, Htmp, NN);
    if (z1f32)
      agg_kernel<false><<<ga, 256, 0, stream>>>(Htmp, row_ptr, csr, dis, b1 + h * 64,
                                                Z1, 128, h * 64, 1, NN);
    else
      agg_kernel<true><<<ga, 256, 0, stream>>>(Htmp, row_ptr, csr, dis, b1 + h * 64,
                                               Z1, 128, h * 64, 1, NN);
  }

  // ---- Layer 2 ----
  if (z1f32)
    gemm_scale_kernel<false><<<gx, 256, 0, stream>>>(Z1, W2, 64, 0, dis, Htmp, NN);
  else
    gemm_scale_kernel<true><<<gx, 256, 0, stream>>>(Z1, W2, 64, 0, dis, Htmp, NN);
  agg_kernel<false><<<ga, 256, 0, stream>>>(Htmp, row_ptr, csr, dis, b2, out, 64, 0, 0, NN);
}

// Round 4
// 248.640 us; speedup vs baseline: 1.6632x; 1.2079x over previous
//
#include <hip/hip_runtime.h>
#include <hip/hip_bf16.h>

#define NN 50000
#define NE 640000
#define NB 196  // ceil((NN+1)/256)

// ---------------- CSR (dest-keyed) build ----------------

__global__ void count_kernel(const int* __restrict__ col, int* __restrict__ cnt, int n) {
  int i = blockIdx.x * blockDim.x + threadIdx.x;
  if (i < n) atomicAdd(&cnt[col[i]], 1);
}

__global__ __launch_bounds__(256) void block_sum_kernel(const int* __restrict__ cnt,
                                                        int* __restrict__ bsum, int n) {
  __shared__ int ws[4];
  const int tid = threadIdx.x;
  const int t = blockIdx.x * 256 + tid;
  int c = (t < n) ? cnt[t] : 0;
  int s = c;
#pragma unroll
  for (int off = 1; off < 64; off <<= 1) s += __shfl_xor(s, off);
  if ((tid & 63) == 0) ws[tid >> 6] = s;
  __syncthreads();
  if (tid == 0) bsum[blockIdx.x] = ws[0] + ws[1] + ws[2] + ws[3];
}

__global__ __launch_bounds__(256) void scan_bsum_kernel(const int* __restrict__ bsum,
                                                        int* __restrict__ boff, int nb) {
  __shared__ int s[256];
  const int tid = threadIdx.x;
  int v = (tid < nb) ? bsum[tid] : 0;
  s[tid] = v;
  __syncthreads();
  for (int off = 1; off < 256; off <<= 1) {
    int u = (tid >= off) ? s[tid - off] : 0;
    __syncthreads();
    s[tid] += u;
    __syncthreads();
  }
  if (tid < nb) boff[tid] = s[tid] - v;  // exclusive
}

__global__ __launch_bounds__(256) void write_rowptr_kernel(
    const int* __restrict__ cnt, const int* __restrict__ boff,
    int* __restrict__ row_ptr, float* __restrict__ dis, int n) {
  __shared__ int wsum[4];
  const int tid = threadIdx.x;
  const int t = blockIdx.x * 256 + tid;
  const int lane = tid & 63, w = tid >> 6;
  int c = (t < n) ? cnt[t] : 0;
  int inc = c;
#pragma unroll
  for (int off = 1; off < 64; off <<= 1) {
    int u = __shfl_up(inc, off);
    if (lane >= off) inc += u;
  }
  if (lane == 63) wsum[w] = inc;
  __syncthreads();
  int wo = 0;
  for (int i = 0; i < w; ++i) wo += wsum[i];
  int excl = boff[blockIdx.x] + wo + inc - c;
  if (t <= n) row_ptr[t] = excl;
  if (t < n) dis[t] = rsqrtf((float)(c + 1));
}

__global__ void fill_kernel(const int* __restrict__ row, const int* __restrict__ col,
                            const int* __restrict__ row_ptr, int* __restrict__ fillc,
                            int* __restrict__ csr, int n) {
  int i = blockIdx.x * blockDim.x + threadIdx.x;
  if (i < n) {
    int c = col[i];
    int p = row_ptr[c] + atomicAdd(&fillc[c], 1);
    csr[p] = row[i];
  }
}

// ---------------- GEMM ----------------
// out[r][c] = dis[r] * sum_{k<128} X[r][k] * W[k*ldw + wc0 + c],  c < 64.
// BM=256, BN=64, K tiled 4x32. 256 threads, 8x8 per thread (rows trow+32i).
// LDS pitch 36 -> Xs read banks 4*trow (conflict-free); Ws reads broadcast/2-way.

__device__ __forceinline__ float bfu(unsigned short u) {
  union { unsigned int i; float f; } v;
  v.i = ((unsigned int)u) << 16;
  return v.f;
}

template <bool BF16IN>
__global__ __launch_bounds__(256) void gemm_scale_kernel(
    const void* __restrict__ Xv, const float* __restrict__ W, int ldw, int wc0,
    const float* __restrict__ dis, float* __restrict__ out, int M) {
  __shared__ float Xs[256][36];  // 36 KB (pitch 36: 16B-aligned rows, bank-spread)
  __shared__ float Ws[32][64];   // 8 KB

  const int t = threadIdx.x;
  const int rb = blockIdx.x * 256;
  const int trow = t >> 3;  // 0..31
  const int tcol = t & 7;   // cols tcol*8 .. +7

  float acc[8][8] = {};

  for (int kt = 0; kt < 4; ++kt) {
    __syncthreads();  // previous tile's compute done before restage
#pragma unroll
    for (int j = 0; j < 2; ++j) {
      int f = t + j * 256;  // 0..511
      int k = f >> 4, cq = f & 15;
      *reinterpret_cast<float4*>(&Ws[k][cq * 4]) =
          *reinterpret_cast<const float4*>(&W[(size_t)(kt * 32 + k) * ldw + wc0 + cq * 4]);
    }
#pragma unroll
    for (int j = 0; j < 8; ++j) {
      int f = t + j * 256;  // 0..2047
      int r = f >> 3, kq = f & 7;
      int gr = rb + r;
      float4 v = {0.f, 0.f, 0.f, 0.f};
      if (gr < M) {
        if constexpr (BF16IN) {
          const unsigned short* X = (const unsigned short*)Xv;
          ushort4 u = *reinterpret_cast<const ushort4*>(&X[(size_t)gr * 128 + kt * 32 + kq * 4]);
          v = make_float4(bfu(u.x), bfu(u.y), bfu(u.z), bfu(u.w));
        } else {
          const float* X = (const float*)Xv;
          v = *reinterpret_cast<const float4*>(&X[(size_t)gr * 128 + kt * 32 + kq * 4]);
        }
      }
      *reinterpret_cast<float4*>(&Xs[r][kq * 4]) = v;
    }
    __syncthreads();

#pragma unroll
    for (int kc = 0; kc < 8; ++kc) {
      float4 wv0[4], wv1[4];
#pragma unroll
      for (int k4 = 0; k4 < 4; ++k4) {
        wv0[k4] = *reinterpret_cast<const float4*>(&Ws[kc * 4 + k4][tcol * 8]);
        wv1[k4] = *reinterpret_cast<const float4*>(&Ws[kc * 4 + k4][tcol * 8 + 4]);
      }
#pragma unroll
      for (int i = 0; i < 8; ++i) {
        float4 xv = *reinterpret_cast<const float4*>(&Xs[trow + 32 * i][kc * 4]);
        float xs[4] = {xv.x, xv.y, xv.z, xv.w};
#pragma unroll
        for (int k4 = 0; k4 < 4; ++k4) {
          acc[i][0] += xs[k4] * wv0[k4].x;
          acc[i][1] += xs[k4] * wv0[k4].y;
          acc[i][2] += xs[k4] * wv0[k4].z;
          acc[i][3] += xs[k4] * wv0[k4].w;
          acc[i][4] += xs[k4] * wv1[k4].x;
          acc[i][5] += xs[k4] * wv1[k4].y;
          acc[i][6] += xs[k4] * wv1[k4].z;
          acc[i][7] += xs[k4] * wv1[k4].w;
        }
      }
    }
  }

#pragma unroll
  for (int i = 0; i < 8; ++i) {
    int r = rb + trow + 32 * i;
    if (r < M) {
      float d = dis[r];
      float4 o0 = {acc[i][0] * d, acc[i][1] * d, acc[i][2] * d, acc[i][3] * d};
      float4 o1 = {acc[i][4] * d, acc[i][5] * d, acc[i][6] * d, acc[i][7] * d};
      *reinterpret_cast<float4*>(&out[(size_t)r * 64 + tcol * 8]) = o0;
      *reinterpret_cast<float4*>(&out[(size_t)r * 64 + tcol * 8 + 4]) = o1;
    }
  }
}

// ---------------- Aggregation ----------------
// out[node*ldo + oc0 + lane] = act( dis[node]*(sum_src Hs[src][lane] + Hs[node][lane]) + bias[lane] )
// One wave per node, lane = channel. Unroll-4 gather with independent accumulators (ILP).

template <bool BF16OUT>
__global__ __launch_bounds__(256) void agg_kernel(
    const float* __restrict__ Hs, const int* __restrict__ row_ptr,
    const int* __restrict__ csr, const float* __restrict__ dis,
    const float* __restrict__ bias, void* __restrict__ outv,
    int ldo, int oc0, int relu, int n) {
  const int lane = threadIdx.x & 63;
  const int node = blockIdx.x * 4 + (threadIdx.x >> 6);
  if (node >= n) return;

  float a0 = Hs[(size_t)node * 64 + lane];  // self-loop term
  float a1 = 0.f, a2 = 0.f, a3 = 0.f;
  const int s0 = row_ptr[node], s1 = row_ptr[node + 1];
  for (int e = s0; e < s1; e += 64) {
    int m = s1 - e;
    if (m > 64) m = 64;
    int idx = 0;
    if (lane < m) idx = csr[e + lane];
    int j = 0;
    for (; j + 4 <= m; j += 4) {
      int i0 = __shfl(idx, j);
      int i1 = __shfl(idx, j + 1);
      int i2 = __shfl(idx, j + 2);
      int i3 = __shfl(idx, j + 3);
      float v0 = Hs[(size_t)i0 * 64 + lane];
      float v1 = Hs[(size_t)i1 * 64 + lane];
      float v2 = Hs[(size_t)i2 * 64 + lane];
      float v3 = Hs[(size_t)i3 * 64 + lane];
      a0 += v0; a1 += v1; a2 += v2; a3 += v3;
    }
    for (; j < m; ++j) a0 += Hs[(size_t)__shfl(idx, j) * 64 + lane];
  }
  float o = ((a0 + a1) + (a2 + a3)) * dis[node] + bias[lane];
  if (relu) o = fmaxf(o, 0.0f);
  if constexpr (BF16OUT) {
    __hip_bfloat16* out = (__hip_bfloat16*)outv;
    out[(size_t)node * ldo + oc0 + lane] = __float2bfloat16(o);
  } else {
    float* out = (float*)outv;
    out[(size_t)node * ldo + oc0 + lane] = o;
  }
}

// ---------------- launch ----------------

extern "C" void kernel_launch(void* const* d_in, const int* in_sizes, int n_in,
                              void* d_out, int out_size, void* d_ws, size_t ws_size,
                              hipStream_t stream) {
  const float* x  = (const float*)d_in[0];
  const int*   ei = (const int*)d_in[1];
  const float* W1 = (const float*)d_in[2];
  const float* b1 = (const float*)d_in[3];
  const float* W2 = (const float*)d_in[4];
  const float* b2 = (const float*)d_in[5];
  float* out = (float*)d_out;

  const int* row = ei;        // source nodes
  const int* col = ei + NE;   // destination nodes

  char* ws = (char*)d_ws;
  size_t off = 0;
  auto alloc = [&](size_t bytes) -> void* {
    off = (off + 255) & ~(size_t)255;
    void* p = ws + off;
    off += bytes;
    return p;
  };

  int* cnt     = (int*)alloc((size_t)2 * NN * sizeof(int));  // cnt | fillc contiguous
  int* fillc   = cnt + NN;
  int* row_ptr = (int*)alloc((size_t)(NN + 1) * sizeof(int));
  int* csr     = (int*)alloc((size_t)NE * sizeof(int));
  float* dis   = (float*)alloc((size_t)NN * sizeof(float));
  int* bsum    = (int*)alloc((size_t)NB * sizeof(int));
  int* boff    = (int*)alloc((size_t)NB * sizeof(int));
  float* Htmp  = (float*)alloc((size_t)NN * 64 * sizeof(float));  // GEMM output slice, reused 3x

  size_t z1_f32_need;
  {
    size_t o2 = (off + 255) & ~(size_t)255;
    z1_f32_need = o2 + (size_t)NN * 128 * sizeof(float);
  }
  const bool z1f32 = (ws_size >= z1_f32_need);
  void* Z1 = alloc((size_t)NN * 128 * (z1f32 ? sizeof(float) : sizeof(__hip_bfloat16)));

  hipMemsetAsync(cnt, 0, (size_t)2 * NN * sizeof(int), stream);
  count_kernel<<<NE / 256, 256, 0, stream>>>(col, cnt, NE);
  block_sum_kernel<<<NB, 256, 0, stream>>>(cnt, bsum, NN);
  scan_bsum_kernel<<<1, 256, 0, stream>>>(bsum, boff, NB);
  write_rowptr_kernel<<<NB, 256, 0, stream>>>(cnt, boff, row_ptr, dis, NN);
  fill_kernel<<<NE / 256, 256, 0, stream>>>(row, col, row_ptr, fillc, csr, NE);

  const int gx = (NN + 255) / 256;
  const int ga = (NN + 3) / 4;

  // ---- Layer 1: two 64-col passes ----
  for (int h = 0; h < 2; ++h) {
    gemm_scale_kernel<false><<<gx, 256, 0, stream>>>(x, W1, 128, h * 64, dis, Htmp, NN);
    if (z1f32)
      agg_kernel<false><<<ga, 256, 0, stream>>>(Htmp, row_ptr, csr, dis, b1 + h * 64,
                                                Z1, 128, h * 64, 1, NN);
    else
      agg_kernel<true><<<ga, 256, 0, stream>>>(Htmp, row_ptr, csr, dis, b1 + h * 64,
                                               Z1, 128, h * 64, 1, NN);
  }

  // ---- Layer 2 ----
  if (z1f32)
    gemm_scale_kernel<false><<<gx, 256, 0, stream>>>(Z1, W2, 64, 0, dis, Htmp, NN);
  else
    gemm_scale_kernel<true><<<gx, 256, 0, stream>>>(Z1, W2, 64, 0, dis, Htmp, NN);
  agg_kernel<false><<<ga, 256, 0, stream>>>(Htmp, row_ptr, csr, dis, b2, out, 64, 0, 0, NN);
}

// Round 5
// 166.169 us; speedup vs baseline: 2.4887x; 1.4963x over previous
//
#include <hip/hip_runtime.h>

#define NN 50000
#define NE 640000
#define NB 196  // ceil((NN+1)/256)

typedef __attribute__((ext_vector_type(8))) short s8v;
typedef __attribute__((ext_vector_type(4))) float f4v;

__device__ __forceinline__ unsigned short f2bf(float x) {  // RNE f32->bf16
  unsigned int u = __float_as_uint(x);
  return (unsigned short)((u + 0x7fffu + ((u >> 16) & 1u)) >> 16);
}
__device__ __forceinline__ float bfval(unsigned short h) {
  return __uint_as_float((unsigned int)h << 16);
}
__device__ __forceinline__ float2 bfpair(unsigned int u) {
  float2 r;
  r.x = __uint_as_float((u & 0xffffu) << 16);
  r.y = __uint_as_float(u & 0xffff0000u);
  return r;
}

// ---------------- CSR (dest-keyed) build ----------------

__global__ void count_kernel(const int* __restrict__ col, int* __restrict__ cnt, int n) {
  int i = blockIdx.x * blockDim.x + threadIdx.x;
  if (i < n) atomicAdd(&cnt[col[i]], 1);
}

__global__ __launch_bounds__(256) void block_sum_kernel(const int* __restrict__ cnt,
                                                        int* __restrict__ bsum, int n) {
  __shared__ int ws[4];
  const int tid = threadIdx.x;
  const int t = blockIdx.x * 256 + tid;
  int c = (t < n) ? cnt[t] : 0;
  int s = c;
#pragma unroll
  for (int off = 1; off < 64; off <<= 1) s += __shfl_xor(s, off);
  if ((tid & 63) == 0) ws[tid >> 6] = s;
  __syncthreads();
  if (tid == 0) bsum[blockIdx.x] = ws[0] + ws[1] + ws[2] + ws[3];
}

__global__ __launch_bounds__(256) void scan_bsum_kernel(const int* __restrict__ bsum,
                                                        int* __restrict__ boff, int nb) {
  __shared__ int s[256];
  const int tid = threadIdx.x;
  int v = (tid < nb) ? bsum[tid] : 0;
  s[tid] = v;
  __syncthreads();
  for (int off = 1; off < 256; off <<= 1) {
    int u = (tid >= off) ? s[tid - off] : 0;
    __syncthreads();
    s[tid] += u;
    __syncthreads();
  }
  if (tid < nb) boff[tid] = s[tid] - v;  // exclusive
}

__global__ __launch_bounds__(256) void write_rowptr_kernel(
    const int* __restrict__ cnt, const int* __restrict__ boff,
    int* __restrict__ row_ptr, float* __restrict__ dis, int n) {
  __shared__ int wsum[4];
  const int tid = threadIdx.x;
  const int t = blockIdx.x * 256 + tid;
  const int lane = tid & 63, w = tid >> 6;
  int c = (t < n) ? cnt[t] : 0;
  int inc = c;
#pragma unroll
  for (int off = 1; off < 64; off <<= 1) {
    int u = __shfl_up(inc, off);
    if (lane >= off) inc += u;
  }
  if (lane == 63) wsum[w] = inc;
  __syncthreads();
  int wo = 0;
  for (int i = 0; i < w; ++i) wo += wsum[i];
  int excl = boff[blockIdx.x] + wo + inc - c;
  if (t <= n) row_ptr[t] = excl;
  if (t < n) dis[t] = rsqrtf((float)(c + 1));
}

__global__ void fill_kernel(const int* __restrict__ row, const int* __restrict__ col,
                            const int* __restrict__ row_ptr, int* __restrict__ fillc,
                            int* __restrict__ csr, int n) {
  int i = blockIdx.x * blockDim.x + threadIdx.x;
  if (i < n) {
    int c = col[i];
    int p = row_ptr[c] + atomicAdd(&fillc[c], 1);
    csr[p] = row[i];
  }
}

// ---------------- W prep: transpose + split f32 -> bf16 hi/lo ----------------
// Wt1[c][k] = split(W1[k][c]) (128x128); Wt2[c][k] = split(W2[k][c]) (64x128)

__global__ __launch_bounds__(256) void wprep_kernel(
    const float* __restrict__ W1, const float* __restrict__ W2,
    unsigned short* __restrict__ wt1h, unsigned short* __restrict__ wt1l,
    unsigned short* __restrict__ wt2h, unsigned short* __restrict__ wt2l) {
  int idx = blockIdx.x * 256 + threadIdx.x;  // 0..24575
  if (idx < 16384) {
    int c = idx >> 7, k = idx & 127;
    float w = W1[k * 128 + c];
    unsigned short h = f2bf(w);
    wt1h[idx] = h;
    wt1l[idx] = f2bf(w - bfval(h));
  } else if (idx < 24576) {
    int i2 = idx - 16384;
    int c = i2 >> 7, k = i2 & 127;
    float w = W2[k * 64 + c];
    unsigned short h = f2bf(w);
    wt2h[i2] = h;
    wt2l[i2] = f2bf(w - bfval(h));
  }
}

// ---------------- MFMA GEMM ----------------
// out[r][c] = dis[r] * sum_{k<128} A[r][k] * Wt[c][k]
// ASPLIT: A is f32, split hi/lo on the fly (3 mfma terms); else A is bf16 (2 terms).
// 256 threads = 4 waves; wave tile 32(M) x 64(N) via 16x16x32 bf16 mfma.
// A-frag: row=lane&15, k=(lane>>4)*8+j ; B-frag: col=lane&15, same k
// C/D: col=lane&15, row=(lane>>4)*4+reg   [guide §3, m89/m91-verified]

template <int NCOLS, bool ASPLIT, bool OUTBF16>
__global__ __launch_bounds__(256) void gemm_mfma_kernel(
    const void* __restrict__ Av, const unsigned short* __restrict__ Bth,
    const unsigned short* __restrict__ Btl, const float* __restrict__ dis,
    void* __restrict__ outv, int M) {
  constexpr int WCOL = NCOLS / 64;   // waves along cols
  constexpr int WROW = 4 / WCOL;     // waves along rows
  constexpr int BM = WROW * 32;      // block rows (64 or 128)
  constexpr int P = 40;              // LDS pitch in bf16 (16B-aligned, 2-way free)

  __shared__ unsigned short Ah[BM][P];
  __shared__ unsigned short Al[ASPLIT ? BM : 1][ASPLIT ? P : 1];
  __shared__ unsigned short Bh[NCOLS][P];
  __shared__ unsigned short Bl[NCOLS][P];

  const int t = threadIdx.x;
  const int lane = t & 63;
  const int l15 = lane & 15;
  const int lg = lane >> 4;
  const int wv = t >> 6;
  const int wr = wv % WROW;
  const int wc = wv / WROW;
  const int rb = blockIdx.x * BM;

  f4v acc[2][4];
#pragma unroll
  for (int i = 0; i < 2; ++i)
#pragma unroll
    for (int j = 0; j < 4; ++j) acc[i][j] = (f4v){0.f, 0.f, 0.f, 0.f};

  for (int kt = 0; kt < 4; ++kt) {
    if (kt) __syncthreads();
    // stage B tile [NCOLS][32] hi+lo
#pragma unroll
    for (int f = t; f < NCOLS * 4; f += 256) {
      int c = f >> 2, kq = f & 3;
      *reinterpret_cast<int4*>(&Bh[c][kq * 8]) =
          *reinterpret_cast<const int4*>(&Bth[c * 128 + kt * 32 + kq * 8]);
      *reinterpret_cast<int4*>(&Bl[c][kq * 8]) =
          *reinterpret_cast<const int4*>(&Btl[c * 128 + kt * 32 + kq * 8]);
    }
    // stage A tile [BM][32]
    if constexpr (ASPLIT) {
      const float* A = (const float*)Av;
#pragma unroll
      for (int j = 0; j < 2; ++j) {
        int f = t + j * 256;  // 512 float4 units (BM=64: 64*8)
        int r = f >> 3, kq = f & 7;
        float4 v = make_float4(0.f, 0.f, 0.f, 0.f);
        if (rb + r < M)
          v = *reinterpret_cast<const float4*>(&A[(size_t)(rb + r) * 128 + kt * 32 + kq * 4]);
        ushort4 hv, lv;
        hv.x = f2bf(v.x); hv.y = f2bf(v.y); hv.z = f2bf(v.z); hv.w = f2bf(v.w);
        lv.x = f2bf(v.x - bfval(hv.x)); lv.y = f2bf(v.y - bfval(hv.y));
        lv.z = f2bf(v.z - bfval(hv.z)); lv.w = f2bf(v.w - bfval(hv.w));
        *reinterpret_cast<ushort4*>(&Ah[r][kq * 4]) = hv;
        *reinterpret_cast<ushort4*>(&Al[r][kq * 4]) = lv;
      }
    } else {
      const unsigned short* A = (const unsigned short*)Av;
#pragma unroll
      for (int j = 0; j < 2; ++j) {
        int f = t + j * 256;  // 512 units of 8 bf16 (BM=128: 128*4)
        int r = f >> 2, kq = f & 3;
        int4 v = {0, 0, 0, 0};
        if (rb + r < M)
          v = *reinterpret_cast<const int4*>(&A[(size_t)(rb + r) * 128 + kt * 32 + kq * 8]);
        *reinterpret_cast<int4*>(&Ah[r][kq * 8]) = v;
      }
    }
    __syncthreads();

    s8v afh[2], afl[2];
#pragma unroll
    for (int rg = 0; rg < 2; ++rg) {
      afh[rg] = *reinterpret_cast<const s8v*>(&Ah[wr * 32 + rg * 16 + l15][lg * 8]);
      if constexpr (ASPLIT)
        afl[rg] = *reinterpret_cast<const s8v*>(&Al[wr * 32 + rg * 16 + l15][lg * 8]);
    }
#pragma unroll
    for (int cg = 0; cg < 4; ++cg) {
      s8v bh = *reinterpret_cast<const s8v*>(&Bh[wc * 64 + cg * 16 + l15][lg * 8]);
      s8v bl = *reinterpret_cast<const s8v*>(&Bl[wc * 64 + cg * 16 + l15][lg * 8]);
#pragma unroll
      for (int rg = 0; rg < 2; ++rg) {
        acc[rg][cg] = __builtin_amdgcn_mfma_f32_16x16x32_bf16(afh[rg], bh, acc[rg][cg], 0, 0, 0);
        acc[rg][cg] = __builtin_amdgcn_mfma_f32_16x16x32_bf16(afh[rg], bl, acc[rg][cg], 0, 0, 0);
        if constexpr (ASPLIT)
          acc[rg][cg] = __builtin_amdgcn_mfma_f32_16x16x32_bf16(afl[rg], bh, acc[rg][cg], 0, 0, 0);
      }
    }
  }

  // epilogue: scale by dis, store
  float dv[2][4];
#pragma unroll
  for (int rg = 0; rg < 2; ++rg)
#pragma unroll
    for (int g = 0; g < 4; ++g) {
      int r = rb + wr * 32 + rg * 16 + lg * 4 + g;
      dv[rg][g] = (r < M) ? dis[r] : 0.f;
    }
#pragma unroll
  for (int rg = 0; rg < 2; ++rg)
#pragma unroll
    for (int cg = 0; cg < 4; ++cg) {
      int colc = wc * 64 + cg * 16 + l15;
#pragma unroll
      for (int g = 0; g < 4; ++g) {
        int r = rb + wr * 32 + rg * 16 + lg * 4 + g;
        if (r < M) {
          float o = acc[rg][cg][g] * dv[rg][g];
          if constexpr (OUTBF16)
            ((unsigned short*)outv)[(size_t)r * NCOLS + colc] = f2bf(o);
          else
            ((float*)outv)[(size_t)r * NCOLS + colc] = o;
        }
      }
    }
}

// ---------------- Aggregation ----------------

// bf16 in [n][128] (as uints), bf16 out [n][128], +bias, relu. 2 ch/lane.
__global__ __launch_bounds__(256) void agg_bf16_kernel(
    const unsigned int* __restrict__ H, const int* __restrict__ row_ptr,
    const int* __restrict__ csr, const float* __restrict__ dis,
    const float* __restrict__ bias, unsigned int* __restrict__ Z, int n) {
  const int lane = threadIdx.x & 63;
  const int node = blockIdx.x * 4 + (threadIdx.x >> 6);
  if (node >= n) return;

  float2 a0 = bfpair(H[(size_t)node * 64 + lane]);  // self-loop
  float2 a1 = make_float2(0.f, 0.f), a2 = make_float2(0.f, 0.f), a3 = make_float2(0.f, 0.f);
  const int s0 = row_ptr[node], s1 = row_ptr[node + 1];
  for (int e = s0; e < s1; e += 64) {
    int m = s1 - e;
    if (m > 64) m = 64;
    int idx = 0;
    if (lane < m) idx = csr[e + lane];
    int j = 0;
    for (; j + 4 <= m; j += 4) {
      int i0 = __shfl(idx, j);
      int i1 = __shfl(idx, j + 1);
      int i2 = __shfl(idx, j + 2);
      int i3 = __shfl(idx, j + 3);
      float2 v0 = bfpair(H[(size_t)i0 * 64 + lane]);
      float2 v1 = bfpair(H[(size_t)i1 * 64 + lane]);
      float2 v2 = bfpair(H[(size_t)i2 * 64 + lane]);
      float2 v3 = bfpair(H[(size_t)i3 * 64 + lane]);
      a0.x += v0.x; a0.y += v0.y;
      a1.x += v1.x; a1.y += v1.y;
      a2.x += v2.x; a2.y += v2.y;
      a3.x += v3.x; a3.y += v3.y;
    }
    for (; j < m; ++j) {
      float2 v = bfpair(H[(size_t)__shfl(idx, j) * 64 + lane]);
      a0.x += v.x; a0.y += v.y;
    }
  }
  const float d = dis[node];
  float2 b = *reinterpret_cast<const float2*>(&bias[lane * 2]);
  float ox = fmaxf((a0.x + a1.x + a2.x + a3.x) * d + b.x, 0.f);
  float oy = fmaxf((a0.y + a1.y + a2.y + a3.y) * d + b.y, 0.f);
  Z[(size_t)node * 64 + lane] = (unsigned int)f2bf(ox) | ((unsigned int)f2bf(oy) << 16);
}

// f32 in [n][64], f32 out [n][64], +bias (no relu). 1 ch/lane.
__global__ __launch_bounds__(256) void agg_f32_kernel(
    const float* __restrict__ Hs, const int* __restrict__ row_ptr,
    const int* __restrict__ csr, const float* __restrict__ dis,
    const float* __restrict__ bias, float* __restrict__ out, int n) {
  const int lane = threadIdx.x & 63;
  const int node = blockIdx.x * 4 + (threadIdx.x >> 6);
  if (node >= n) return;

  float a0 = Hs[(size_t)node * 64 + lane];  // self-loop
  float a1 = 0.f, a2 = 0.f, a3 = 0.f;
  const int s0 = row_ptr[node], s1 = row_ptr[node + 1];
  for (int e = s0; e < s1; e += 64) {
    int m = s1 - e;
    if (m > 64) m = 64;
    int idx = 0;
    if (lane < m) idx = csr[e + lane];
    int j = 0;
    for (; j + 4 <= m; j += 4) {
      int i0 = __shfl(idx, j);
      int i1 = __shfl(idx, j + 1);
      int i2 = __shfl(idx, j + 2);
      int i3 = __shfl(idx, j + 3);
      float v0 = Hs[(size_t)i0 * 64 + lane];
      float v1 = Hs[(size_t)i1 * 64 + lane];
      float v2 = Hs[(size_t)i2 * 64 + lane];
      float v3 = Hs[(size_t)i3 * 64 + lane];
      a0 += v0; a1 += v1; a2 += v2; a3 += v3;
    }
    for (; j < m; ++j) a0 += Hs[(size_t)__shfl(idx, j) * 64 + lane];
  }
  float o = ((a0 + a1) + (a2 + a3)) * dis[node] + bias[lane];
  out[(size_t)node * 64 + lane] = o;
}

// ---------------- launch ----------------

extern "C" void kernel_launch(void* const* d_in, const int* in_sizes, int n_in,
                              void* d_out, int out_size, void* d_ws, size_t ws_size,
                              hipStream_t stream) {
  const float* x  = (const float*)d_in[0];
  const int*   ei = (const int*)d_in[1];
  const float* W1 = (const float*)d_in[2];
  const float* b1 = (const float*)d_in[3];
  const float* W2 = (const float*)d_in[4];
  const float* b2 = (const float*)d_in[5];
  float* out = (float*)d_out;

  const int* row = ei;        // source nodes
  const int* col = ei + NE;   // destination nodes

  char* ws = (char*)d_ws;
  size_t off = 0;
  auto alloc = [&](size_t bytes) -> void* {
    off = (off + 255) & ~(size_t)255;
    void* p = ws + off;
    off += bytes;
    return p;
  };

  int* cnt     = (int*)alloc((size_t)2 * NN * sizeof(int));  // cnt | fillc
  int* fillc   = cnt + NN;
  int* row_ptr = (int*)alloc((size_t)(NN + 1) * sizeof(int));
  int* csr     = (int*)alloc((size_t)NE * sizeof(int));
  float* dis   = (float*)alloc((size_t)NN * sizeof(float));
  int* bsum    = (int*)alloc((size_t)NB * sizeof(int));
  int* boff    = (int*)alloc((size_t)NB * sizeof(int));
  // HT region: bf16 [NN][128] for layer-1 GEMM out, then f32 [NN][64] for layer-2 (same bytes)
  unsigned short* HT16 = (unsigned short*)alloc((size_t)NN * 128 * 2);
  float* HT32 = (float*)HT16;
  unsigned int* HTu = (unsigned int*)HT16;
  unsigned short* Z1 = (unsigned short*)alloc((size_t)NN * 128 * 2);
  unsigned int* Z1u = (unsigned int*)Z1;

  // W split tables alias the cnt region (dead after fill_kernel): 96KB < 200KB
  unsigned short* wt1h = (unsigned short*)cnt;
  unsigned short* wt1l = wt1h + 128 * 128;
  unsigned short* wt2h = wt1l + 128 * 128;
  unsigned short* wt2l = wt2h + 64 * 128;

  hipMemsetAsync(cnt, 0, (size_t)2 * NN * sizeof(int), stream);
  count_kernel<<<NE / 256, 256, 0, stream>>>(col, cnt, NE);
  block_sum_kernel<<<NB, 256, 0, stream>>>(cnt, bsum, NN);
  scan_bsum_kernel<<<1, 256, 0, stream>>>(bsum, boff, NB);
  write_rowptr_kernel<<<NB, 256, 0, stream>>>(cnt, boff, row_ptr, dis, NN);
  fill_kernel<<<NE / 256, 256, 0, stream>>>(row, col, row_ptr, fillc, csr, NE);
  wprep_kernel<<<96, 256, 0, stream>>>(W1, W2, wt1h, wt1l, wt2h, wt2l);  // after fill: aliases cnt

  const int ga = (NN + 3) / 4;

  // Layer 1: HT16 = bf16( dis .* (X @ W1) )  [NN][128], one pass
  gemm_mfma_kernel<128, true, true><<<(NN + 63) / 64, 256, 0, stream>>>(
      x, wt1h, wt1l, dis, HT16, NN);
  agg_bf16_kernel<<<ga, 256, 0, stream>>>(HTu, row_ptr, csr, dis, b1, Z1u, NN);

  // Layer 2: HT32 = dis .* (Z1 @ W2)  [NN][64]
  gemm_mfma_kernel<64, false, false><<<(NN + 127) / 128, 256, 0, stream>>>(
      Z1, wt2h, wt2l, dis, HT32, NN);
  agg_f32_kernel<<<ga, 256, 0, stream>>>(HT32, row_ptr, csr, dis, b2, out, NN);
}